// Round 6
// baseline (95.330 us; speedup 1.0000x reference)
//
#include <hip/hip_runtime.h>

// MomentAccumulatorObserver: scatter (permutation) -> gather-products -> add carry.
// N_NODES = 1e6, N_EDGES = 8e6.
// r4 post-mortem: gather service rate pinned at ~0.3 line-req/cy/CU across
// MLP 4/8/16 and table 4/2 MB -> per-CU TCP miss-queue (~60 entries x ~200cy
// L2 latency). r5 discriminating experiment: L1-BYPASS gathers via agent-scope
// atomic loads (sc-bit loads: TCP no-allocate, read from L2). If the same
// MSHR pool bounds bypass requests -> null -> declare roofline. If not,
// throughput rises toward the L2-side request ceiling.

typedef float v4f __attribute__((ext_vector_type(4)));
typedef int   v4i __attribute__((ext_vector_type(4)));
typedef unsigned short u16;

__device__ __forceinline__ float bf2f(u16 v) {
    unsigned u = ((unsigned)v) << 16;
    return __builtin_bit_cast(float, u);
}
__device__ __forceinline__ u16 f2bf(float f) {
    unsigned x = __builtin_bit_cast(unsigned, f);
    unsigned r = (x + 0x7FFFu + ((x >> 16) & 1u)) >> 16;  // RNE; inputs are finite
    return (u16)r;
}
// L1-bypass gather: relaxed agent-scope load -> global_load_ushort with sc
// bits set (TCP miss-and-no-allocate, served from L2).
__device__ __forceinline__ u16 gat(const u16* __restrict__ p) {
    return __hip_atomic_load(p, __ATOMIC_RELAXED, __HIP_MEMORY_SCOPE_AGENT);
}

// Stage 1: permutation scatter -> bf16 table (2 MB).
__global__ __launch_bounds__(256) void scatter_kernel(
        const float* __restrict__ vals, const int* __restrict__ sidx,
        u16* __restrict__ flatb, int n) {
    int i = blockIdx.x * blockDim.x + threadIdx.x;
    int n4 = n >> 2;
    if (i < n4) {
        v4i s = __builtin_nontemporal_load(&((const v4i*)sidx)[i]);
        v4f v = __builtin_nontemporal_load(&((const v4f*)vals)[i]);
        flatb[s.x] = f2bf(v.x);
        flatb[s.y] = f2bf(v.y);
        flatb[s.z] = f2bf(v.z);
        flatb[s.w] = f2bf(v.w);
    }
    if (i < (n & 3)) {
        int t = (n & ~3) + i;
        flatb[sidx[t]] = f2bf(vals[t]);
    }
}

// Stage 2 (fused): mem2 (8 edges/thread, 16 L1-bypass gathers) then mem1.
__global__ __launch_bounds__(256) void fused21_kernel(
        const u16* __restrict__ flatb,
        const int* __restrict__ ms2, const float* __restrict__ carry2,
        float* __restrict__ out2,
        const int* __restrict__ ms1, const float* __restrict__ carry1,
        float* __restrict__ out1,
        int n_edges, int n_nodes) {
    int i = blockIdx.x * blockDim.x + threadIdx.x;

    // ---- mem2: pair moments ----
    int n8 = n_edges >> 3;
    if (i < n8) {
        const v4i* m = (const v4i*)ms2;   // 4 x v4i = 8 edges
        v4i idx[4];
#pragma unroll
        for (int k = 0; k < 4; ++k)
            idx[k] = __builtin_nontemporal_load(&m[4 * i + k]);
        u16 g[16];
#pragma unroll
        for (int k = 0; k < 4; ++k) {
            g[4 * k + 0] = gat(&flatb[idx[k].x]);
            g[4 * k + 1] = gat(&flatb[idx[k].y]);
            g[4 * k + 2] = gat(&flatb[idx[k].z]);
            g[4 * k + 3] = gat(&flatb[idx[k].w]);
        }
        v4f c0 = __builtin_nontemporal_load(&((const v4f*)carry2)[2 * i]);
        v4f c1 = __builtin_nontemporal_load(&((const v4f*)carry2)[2 * i + 1]);
        v4f o0, o1;
        o0.x = c0.x + bf2f(g[0])  * bf2f(g[1]);
        o0.y = c0.y + bf2f(g[2])  * bf2f(g[3]);
        o0.z = c0.z + bf2f(g[4])  * bf2f(g[5]);
        o0.w = c0.w + bf2f(g[6])  * bf2f(g[7]);
        o1.x = c1.x + bf2f(g[8])  * bf2f(g[9]);
        o1.y = c1.y + bf2f(g[10]) * bf2f(g[11]);
        o1.z = c1.z + bf2f(g[12]) * bf2f(g[13]);
        o1.w = c1.w + bf2f(g[14]) * bf2f(g[15]);
        __builtin_nontemporal_store(o0, &((v4f*)out2)[2 * i]);
        __builtin_nontemporal_store(o1, &((v4f*)out2)[2 * i + 1]);
    }
    if (i < (n_edges & 7)) {
        int e = (n_edges & ~7) + i;
        out2[e] = carry2[e] + bf2f(gat(&flatb[ms2[2 * e]])) * bf2f(gat(&flatb[ms2[2 * e + 1]]));
    }

    // ---- mem1: singleton moments (coalesced gathers, keep L1 path) ----
    int n4 = n_nodes >> 2;
    if (i < n4) {
        v4i s = __builtin_nontemporal_load(&((const v4i*)ms1)[i]);
        float g0 = bf2f(flatb[s.x]), g1 = bf2f(flatb[s.y]);
        float g2 = bf2f(flatb[s.z]), g3 = bf2f(flatb[s.w]);
        v4f c = __builtin_nontemporal_load(&((const v4f*)carry1)[i]);
        v4f o = {c.x + g0, c.y + g1, c.z + g2, c.w + g3};
        __builtin_nontemporal_store(o, &((v4f*)out1)[i]);
    }
    if (i < (n_nodes & 3)) {
        int t = (n_nodes & ~3) + i;
        out1[t] = carry1[t] + bf2f(flatb[ms1[t]]);
    }
}

extern "C" void kernel_launch(void* const* d_in, const int* in_sizes, int n_in,
                              void* d_out, int out_size, void* d_ws, size_t ws_size,
                              hipStream_t stream) {
    const float* sampled = (const float*)d_in[0];
    const int*   sidx    = (const int*)d_in[1];
    const int*   ms1     = (const int*)d_in[2];
    const int*   ms2     = (const int*)d_in[3];
    const float* carry1  = (const float*)d_in[4];
    const float* carry2  = (const float*)d_in[5];

    const int n_nodes = in_sizes[0];          // 1,000,000
    const int n_edges = in_sizes[5];          // 8,000,000

    u16*   flatb = (u16*)d_ws;                // 2 MB bf16 table
    float* out1  = (float*)d_out;             // [n_nodes]
    float* out2  = out1 + n_nodes;            // [n_edges]

    const int B = 256;

    {
        int nthread = (n_nodes + 3) / 4;
        scatter_kernel<<<(nthread + B - 1) / B, B, 0, stream>>>(
            sampled, sidx, flatb, n_nodes);
    }
    {
        int n8 = (n_edges + 7) / 8;
        int n4 = (n_nodes + 3) / 4;
        int nthread = n8 > n4 ? n8 : n4;
        fused21_kernel<<<(nthread + B - 1) / B, B, 0, stream>>>(
            flatb, ms2, carry2, out2, ms1, carry1, out1, n_edges, n_nodes);
    }
}

// Round 7
// 92.912 us; speedup vs baseline: 1.0260x; 1.0260x over previous
//
#include <hip/hip_runtime.h>

// MomentAccumulatorObserver: scatter (permutation) -> gather-products -> add carry.
// N_NODES = 1e6, N_EDGES = 8e6.
// FINAL CONFIG (r4 reverted): the workload is bound by the per-CU vector-memory
// outstanding-miss pool on random gathers: measured 0.28-0.31 line-req/cy/CU
// across MLP 4/8/16 per thread, table 4/2 MB, fused/unfused, L1-cached/bypass
// (r5 A/B null). Model: ~64 MSHRs / ~210 cy L2-hit latency = 0.30 req/cy/CU
// -> 87 us floor for 16M random line requests; measured fused kernel = 89 us.
//   - single bf16 table (2 MB, L2-resident) in d_ws; err <= |v|*2^-9 << thr.
//   - mem2 (8 edges/thread) + mem1 fused in one dispatch; nt hints on streams
//     only (table stays cache-resident).

typedef float v4f __attribute__((ext_vector_type(4)));
typedef int   v4i __attribute__((ext_vector_type(4)));
typedef unsigned short u16;

__device__ __forceinline__ float bf2f(u16 v) {
    unsigned u = ((unsigned)v) << 16;
    return __builtin_bit_cast(float, u);
}
__device__ __forceinline__ u16 f2bf(float f) {
    unsigned x = __builtin_bit_cast(unsigned, f);
    unsigned r = (x + 0x7FFFu + ((x >> 16) & 1u)) >> 16;  // RNE; inputs are finite
    return (u16)r;
}

// Stage 1: permutation scatter -> bf16 table (2 MB).
__global__ __launch_bounds__(256) void scatter_kernel(
        const float* __restrict__ vals, const int* __restrict__ sidx,
        u16* __restrict__ flatb, int n) {
    int i = blockIdx.x * blockDim.x + threadIdx.x;
    int n4 = n >> 2;
    if (i < n4) {
        v4i s = __builtin_nontemporal_load(&((const v4i*)sidx)[i]);
        v4f v = __builtin_nontemporal_load(&((const v4f*)vals)[i]);
        flatb[s.x] = f2bf(v.x);
        flatb[s.y] = f2bf(v.y);
        flatb[s.z] = f2bf(v.z);
        flatb[s.w] = f2bf(v.w);
    }
    if (i < (n & 3)) {
        int t = (n & ~3) + i;
        flatb[sidx[t]] = f2bf(vals[t]);
    }
}

// Stage 2 (fused): mem2 (8 edges/thread, 16 gathers) then mem1.
__global__ __launch_bounds__(256) void fused21_kernel(
        const u16* __restrict__ flatb,
        const int* __restrict__ ms2, const float* __restrict__ carry2,
        float* __restrict__ out2,
        const int* __restrict__ ms1, const float* __restrict__ carry1,
        float* __restrict__ out1,
        int n_edges, int n_nodes) {
    int i = blockIdx.x * blockDim.x + threadIdx.x;

    // ---- mem2: pair moments ----
    int n8 = n_edges >> 3;
    if (i < n8) {
        const v4i* m = (const v4i*)ms2;   // 4 x v4i = 8 edges
        v4i idx[4];
#pragma unroll
        for (int k = 0; k < 4; ++k)
            idx[k] = __builtin_nontemporal_load(&m[4 * i + k]);
        u16 g[16];
#pragma unroll
        for (int k = 0; k < 4; ++k) {
            g[4 * k + 0] = flatb[idx[k].x];
            g[4 * k + 1] = flatb[idx[k].y];
            g[4 * k + 2] = flatb[idx[k].z];
            g[4 * k + 3] = flatb[idx[k].w];
        }
        v4f c0 = __builtin_nontemporal_load(&((const v4f*)carry2)[2 * i]);
        v4f c1 = __builtin_nontemporal_load(&((const v4f*)carry2)[2 * i + 1]);
        v4f o0, o1;
        o0.x = c0.x + bf2f(g[0])  * bf2f(g[1]);
        o0.y = c0.y + bf2f(g[2])  * bf2f(g[3]);
        o0.z = c0.z + bf2f(g[4])  * bf2f(g[5]);
        o0.w = c0.w + bf2f(g[6])  * bf2f(g[7]);
        o1.x = c1.x + bf2f(g[8])  * bf2f(g[9]);
        o1.y = c1.y + bf2f(g[10]) * bf2f(g[11]);
        o1.z = c1.z + bf2f(g[12]) * bf2f(g[13]);
        o1.w = c1.w + bf2f(g[14]) * bf2f(g[15]);
        __builtin_nontemporal_store(o0, &((v4f*)out2)[2 * i]);
        __builtin_nontemporal_store(o1, &((v4f*)out2)[2 * i + 1]);
    }
    if (i < (n_edges & 7)) {
        int e = (n_edges & ~7) + i;
        out2[e] = carry2[e] + bf2f(flatb[ms2[2 * e]]) * bf2f(flatb[ms2[2 * e + 1]]);
    }

    // ---- mem1: singleton moments (coalesced gathers) ----
    int n4 = n_nodes >> 2;
    if (i < n4) {
        v4i s = __builtin_nontemporal_load(&((const v4i*)ms1)[i]);
        float g0 = bf2f(flatb[s.x]), g1 = bf2f(flatb[s.y]);
        float g2 = bf2f(flatb[s.z]), g3 = bf2f(flatb[s.w]);
        v4f c = __builtin_nontemporal_load(&((const v4f*)carry1)[i]);
        v4f o = {c.x + g0, c.y + g1, c.z + g2, c.w + g3};
        __builtin_nontemporal_store(o, &((v4f*)out1)[i]);
    }
    if (i < (n_nodes & 3)) {
        int t = (n_nodes & ~3) + i;
        out1[t] = carry1[t] + bf2f(flatb[ms1[t]]);
    }
}

extern "C" void kernel_launch(void* const* d_in, const int* in_sizes, int n_in,
                              void* d_out, int out_size, void* d_ws, size_t ws_size,
                              hipStream_t stream) {
    const float* sampled = (const float*)d_in[0];
    const int*   sidx    = (const int*)d_in[1];
    const int*   ms1     = (const int*)d_in[2];
    const int*   ms2     = (const int*)d_in[3];
    const float* carry1  = (const float*)d_in[4];
    const float* carry2  = (const float*)d_in[5];

    const int n_nodes = in_sizes[0];          // 1,000,000
    const int n_edges = in_sizes[5];          // 8,000,000

    u16*   flatb = (u16*)d_ws;                // 2 MB bf16 table
    float* out1  = (float*)d_out;             // [n_nodes]
    float* out2  = out1 + n_nodes;            // [n_edges]

    const int B = 256;

    {
        int nthread = (n_nodes + 3) / 4;
        scatter_kernel<<<(nthread + B - 1) / B, B, 0, stream>>>(
            sampled, sidx, flatb, n_nodes);
    }
    {
        int n8 = (n_edges + 7) / 8;
        int n4 = (n_nodes + 3) / 4;
        int nthread = n8 > n4 ? n8 : n4;
        fused21_kernel<<<(nthread + B - 1) / B, B, 0, stream>>>(
            flatb, ms2, carry2, out2, ms1, carry1, out1, n_edges, n_nodes);
    }
}